// Round 1
// baseline (36.147 us; speedup 1.0000x reference)
//
#include <hip/hip_runtime.h>

// Masked MSE with ragged alignment.
// Row kernel: one block (256 thr) per row, processes S=4096 elements in
// chunks of 1024 (float4/int4 per thread). Block-wide inclusive scan of the
// mask gives each masked element its rank -> gather target[row, rank].
__global__ __launch_bounds__(256) void masked_mse_rows(
    const float* __restrict__ pred,
    const float* __restrict__ target,
    const int*   __restrict__ mask,
    float*       __restrict__ row_sums,
    int S)
{
    const int row  = blockIdx.x;
    const int tid  = threadIdx.x;
    const int lane = tid & 63;
    const int wid  = tid >> 6;

    const float4* __restrict__ p4 = reinterpret_cast<const float4*>(pred + (size_t)row * S);
    const int4*   __restrict__ m4 = reinterpret_cast<const int4*>(mask + (size_t)row * S);
    const float*  __restrict__ trow = target + (size_t)row * S;

    __shared__ int   wsum[4];
    __shared__ float facc[4];

    float acc = 0.0f;
    int running = 0;                       // masked count so far in this row
    const int nchunk = S >> 10;            // S / 1024

    for (int c = 0; c < nchunk; ++c) {
        const int idx = c * 256 + tid;
        const int4   m = m4[idx];
        const float4 p = p4[idx];

        const int b0 = (m.x != 0), b1 = (m.y != 0), b2 = (m.z != 0), b3 = (m.w != 0);
        const int cnt = b0 + b1 + b2 + b3;

        // wave64 inclusive scan of cnt
        int scan = cnt;
        #pragma unroll
        for (int off = 1; off < 64; off <<= 1) {
            int n = __shfl_up(scan, off, 64);
            if (lane >= off) scan += n;
        }
        if (lane == 63) wsum[wid] = scan;
        __syncthreads();

        int wave_off = 0;
        #pragma unroll
        for (int w = 0; w < 4; ++w) wave_off += (w < wid) ? wsum[w] : 0;
        const int total = wsum[0] + wsum[1] + wsum[2] + wsum[3];

        int r = running + wave_off + (scan - cnt);   // exclusive rank of elem 0

        if (b0) { float d = p.x - trow[r]; acc += d * d; ++r; }
        if (b1) { float d = p.y - trow[r]; acc += d * d; ++r; }
        if (b2) { float d = p.z - trow[r]; acc += d * d; ++r; }
        if (b3) { float d = p.w - trow[r]; acc += d * d; ++r; }

        running += total;
        __syncthreads();   // wsum reused next chunk
    }

    // block reduction of acc
    #pragma unroll
    for (int off = 32; off > 0; off >>= 1) acc += __shfl_down(acc, off, 64);
    if (lane == 0) facc[wid] = acc;
    __syncthreads();
    if (tid == 0) row_sums[row] = facc[0] + facc[1] + facc[2] + facc[3];
}

// Deterministic final reduce of B row partials into d_out[0].
__global__ __launch_bounds__(256) void reduce_rows(
    const float* __restrict__ row_sums, float* __restrict__ out, int n)
{
    const int tid = threadIdx.x;
    float acc = 0.0f;
    for (int i = tid; i < n; i += 256) acc += row_sums[i];
    #pragma unroll
    for (int off = 32; off > 0; off >>= 1) acc += __shfl_down(acc, off, 64);
    __shared__ float facc[4];
    if ((tid & 63) == 0) facc[tid >> 6] = acc;
    __syncthreads();
    if (tid == 0) out[0] = facc[0] + facc[1] + facc[2] + facc[3];
}

extern "C" void kernel_launch(void* const* d_in, const int* in_sizes, int n_in,
                              void* d_out, int out_size, void* d_ws, size_t ws_size,
                              hipStream_t stream) {
    const float* pred   = (const float*)d_in[0];
    const float* target = (const float*)d_in[1];
    const int*   mask   = (const int*)d_in[2];
    float* out = (float*)d_out;
    float* row_sums = (float*)d_ws;

    const int S = 4096;
    const int B = in_sizes[0] / S;

    masked_mse_rows<<<B, 256, 0, stream>>>(pred, target, mask, row_sums, S);
    reduce_rows<<<1, 256, 0, stream>>>(row_sums, out, B);
}